// Round 8
// baseline (62.126 us; speedup 1.0000x reference)
//
#include <hip/hip_runtime.h>
#include <hip/hip_bf16.h>

#define NUM_BINS 512
#define T_LEN 256
#define B_LEN 16
#define WIN 101
#define HALF 50
#define NOUT 128

typedef __attribute__((ext_vector_type(8))) short short8;
typedef __attribute__((ext_vector_type(4))) float f32x4;
typedef __attribute__((ext_vector_type(4))) int v4i;

__device__ __forceinline__ unsigned short f2bf(float f) {
    unsigned u = __float_as_uint(f);
    u += 0x7fff + ((u >> 16) & 1);   // round-to-nearest-even
    return (unsigned short)(u >> 16);
}

// ---------------- Kernel 1: histograms (2 frames/block) + fc_w preswizzle ----
// 2048 frame-blocks (2 frames each) + 8 tail blocks converting fc_w to the
// bf16 MFMA B-fragment layout [og][ks][kg][l15][e], zero-padded to K=128.
// All 24 dwordx4 (both frames) issued non-temporally up front: frame-1's HBM
// latency hides under frame-0's atomic stream + reduction (DS pipe is
// co-critical with VMEM here; deep prefetch keeps both pipes fed).
__global__ __launch_bounds__(256, 4) void hist_kernel(const int* __restrict__ frames,
                                                      const float* __restrict__ fc_w,
                                                      __hip_bfloat16* __restrict__ xout,
                                                      unsigned short* __restrict__ fcswz) {
    const int tid = threadIdx.x;
    const int bid = blockIdx.x;

    if (bid >= 2048) {
        const int base = (bid - 2048) * 2048 + tid * 8;
        const int l15 = (base >> 3) & 15;
        const int kg = (base >> 7) & 3;
        const int ks = (base >> 9) & 3;
        const int og = base >> 11;
        const int o = og * 16 + l15;
        short8 v;
        #pragma unroll
        for (int e = 0; e < 8; ++e) {
            const int w = ks * 32 + kg * 8 + e;
            v[e] = (short)((w < WIN) ? f2bf(fc_w[o * WIN + w]) : (unsigned short)0);
        }
        *(short8*)(fcswz + base) = v;
        return;
    }

    __shared__ int hist[2][NUM_BINS];
    __shared__ float red[2][4];

    // Issue ALL loads first (nt: read-once stream, no L1 allocate).
    const v4i* f4 = (const v4i*)(frames + (size_t)bid * 24576);
    v4i r0[12], r1[12];
    #pragma unroll
    for (int i = 0; i < 4; ++i) {
        const int q = (i * 256 + tid) * 3;
        r0[i * 3 + 0] = __builtin_nontemporal_load(f4 + q + 0);
        r0[i * 3 + 1] = __builtin_nontemporal_load(f4 + q + 1);
        r0[i * 3 + 2] = __builtin_nontemporal_load(f4 + q + 2);
    }
    #pragma unroll
    for (int i = 0; i < 4; ++i) {
        const int q = 3072 + (i * 256 + tid) * 3;
        r1[i * 3 + 0] = __builtin_nontemporal_load(f4 + q + 0);
        r1[i * 3 + 1] = __builtin_nontemporal_load(f4 + q + 1);
        r1[i * 3 + 2] = __builtin_nontemporal_load(f4 + q + 2);
    }

    hist[0][tid] = 0; hist[0][tid + 256] = 0;
    hist[1][tid] = 0; hist[1][tid + 256] = 0;
    __syncthreads();

    // frame-0 atomics (vmcnt-gated per chunk; f1 loads still in flight)
    #pragma unroll
    for (int i = 0; i < 4; ++i) {
        v4i a = r0[i * 3 + 0], b = r0[i * 3 + 1], c = r0[i * 3 + 2];
        atomicAdd(&hist[0][((a.x >> 5) << 6) | ((a.y >> 5) << 3) | (a.z >> 5)], 1);
        atomicAdd(&hist[0][((a.w >> 5) << 6) | ((b.x >> 5) << 3) | (b.y >> 5)], 1);
        atomicAdd(&hist[0][((b.z >> 5) << 6) | ((b.w >> 5) << 3) | (c.x >> 5)], 1);
        atomicAdd(&hist[0][((c.y >> 5) << 6) | ((c.z >> 5) << 3) | (c.w >> 5)], 1);
    }
    __syncthreads();   // barrier A: hist[0] final

    const int lane = tid & 63;
    const int wave = tid >> 6;

    // reduce frame 0 while frame-1 loads finish landing
    const int a0 = hist[0][tid];
    const int a1 = hist[0][tid + 256];
    float ss0 = (float)a0 * (float)a0 + (float)a1 * (float)a1;
    #pragma unroll
    for (int off = 32; off; off >>= 1) ss0 += __shfl_down(ss0, off, 64);
    if (lane == 0) red[0][wave] = ss0;

    // frame-1 atomics
    #pragma unroll
    for (int i = 0; i < 4; ++i) {
        v4i a = r1[i * 3 + 0], b = r1[i * 3 + 1], c = r1[i * 3 + 2];
        atomicAdd(&hist[1][((a.x >> 5) << 6) | ((a.y >> 5) << 3) | (a.z >> 5)], 1);
        atomicAdd(&hist[1][((a.w >> 5) << 6) | ((b.x >> 5) << 3) | (b.y >> 5)], 1);
        atomicAdd(&hist[1][((b.z >> 5) << 6) | ((b.w >> 5) << 3) | (c.x >> 5)], 1);
        atomicAdd(&hist[1][((c.y >> 5) << 6) | ((c.z >> 5) << 3) | (c.w >> 5)], 1);
    }
    __syncthreads();   // barrier B: hist[1] final + red[0] visible

    {
        const float inv = 1.0f / sqrtf(red[0][0] + red[0][1] + red[0][2] + red[0][3]);
        __hip_bfloat16* xrow = xout + (size_t)(bid * 2) * NUM_BINS;
        xrow[tid] = __float2bfloat16((float)a0 * inv);
        xrow[tid + 256] = __float2bfloat16((float)a1 * inv);
    }
    const int b0 = hist[1][tid];
    const int b1 = hist[1][tid + 256];
    float ss1 = (float)b0 * (float)b0 + (float)b1 * (float)b1;
    #pragma unroll
    for (int off = 32; off; off >>= 1) ss1 += __shfl_down(ss1, off, 64);
    if (lane == 0) red[1][wave] = ss1;
    __syncthreads();   // barrier C: red[1] visible
    {
        const float inv = 1.0f / sqrtf(red[1][0] + red[1][1] + red[1][2] + red[1][3]);
        __hip_bfloat16* xrow = xout + (size_t)(bid * 2 + 1) * NUM_BINS;
        xrow[tid] = __float2bfloat16((float)b0 * inv);
        xrow[tid + 256] = __float2bfloat16((float)b1 * inv);
    }
}

// ---------------- Kernel 2: MFMA banded sim + window extract + MFMA FC -------
// grid = 256 blocks (XCD = b%8 keeps per-XCD x slice L2-hot), 512 threads.
// Phase 1: wave j computes s-tile j of the 16x128 sim band (16 MFMAs, K=512).
// Phase 2: diagonal extract win[i][w] = sim[i][i+w] -> bf16, zero-pad w>=101.
// Phase 3: wave j computes 16 FC outputs via pre-swizzled bf16 fc_w (4 MFMAs).
__global__ __launch_bounds__(512) void simfc_kernel(const unsigned short* __restrict__ x,
                                                    const unsigned short* __restrict__ fcswz,
                                                    const float* __restrict__ fc_b,
                                                    float* __restrict__ out) {
    __shared__ float sim_lds[16 * 132];
    __shared__ unsigned short win_lds[16 * 136];

    const int bid = blockIdx.x;
    const int b = bid & 15;
    const int tt = bid >> 4;
    const int t0 = tt * 16;
    const int tid = threadIdx.x;
    const int lane = tid & 63;
    const int wave = tid >> 6;   // 0..7
    const int l15 = lane & 15;
    const int kg = lane >> 4;    // k-chunk 0..3

    const unsigned short* xb = x + (size_t)b * T_LEN * NUM_BINS;

    // ---- Phase 1: s-tile `wave`: cols s = t0-50+16*wave .. +15
    {
        f32x4 acc = {0.f, 0.f, 0.f, 0.f};
        const short8 zero8 = {0, 0, 0, 0, 0, 0, 0, 0};
        const int rowA = t0 + l15;
        const int rb = t0 - HALF + 16 * wave + l15;
        const bool vv = (rb >= 0) && (rb < T_LEN);
        const int rc = min(max(rb, 0), T_LEN - 1);
        const unsigned short* pa = xb + (size_t)rowA * NUM_BINS + kg * 8;
        const unsigned short* ps = xb + (size_t)rc * NUM_BINS + kg * 8;
        #pragma unroll
        for (int ks = 0; ks < 16; ++ks) {
            short8 a  = *(const short8*)(pa + ks * 32);
            short8 bb = *(const short8*)(ps + ks * 32);
            bb = vv ? bb : zero8;
            acc = __builtin_amdgcn_mfma_f32_16x16x32_bf16(a, bb, acc, 0, 0, 0);
        }
        #pragma unroll
        for (int r = 0; r < 4; ++r)
            sim_lds[(kg * 4 + r) * 132 + wave * 16 + l15] = acc[r];
    }
    __syncthreads();

    // ---- Phase 2: windowed[i][w] = sim[i][i+w], bf16, zero-pad w>=101.
    if (tid < 256) {
        const int i = tid >> 4;
        const int w8 = (tid & 15) * 8;
        short8 v;
        #pragma unroll
        for (int e = 0; e < 8; ++e) {
            const int w = w8 + e;
            const float fv = (w < WIN) ? sim_lds[i * 132 + i + w] : 0.0f;
            v[e] = (short)f2bf(fv);
        }
        *(short8*)(&win_lds[i * 136 + w8]) = v;
    }
    __syncthreads();

    // ---- Phase 3: wave owns outputs o = wave*16 + l15, K=128 MFMA.
    {
        f32x4 o0 = {0.f, 0.f, 0.f, 0.f};
        const int o = wave * 16 + l15;
        #pragma unroll
        for (int ks = 0; ks < 4; ++ks) {
            short8 a = *(const short8*)(&win_lds[l15 * 136 + ks * 32 + kg * 8]);
            short8 b0 = *(const short8*)(fcswz + ((((wave * 4 + ks) * 4 + kg) * 16 + l15) * 8));
            o0 = __builtin_amdgcn_mfma_f32_16x16x32_bf16(a, b0, o0, 0, 0, 0);
        }
        const float bias = fc_b[o];
        float* ob = out + ((size_t)b * T_LEN + t0) * NOUT;
        #pragma unroll
        for (int r = 0; r < 4; ++r)
            ob[(kg * 4 + r) * NOUT + o] = fmaxf(o0[r] + bias, 0.0f);
    }
}

extern "C" void kernel_launch(void* const* d_in, const int* in_sizes, int n_in,
                              void* d_out, int out_size, void* d_ws, size_t ws_size,
                              hipStream_t stream) {
    const int* frames = (const int*)d_in[0];
    const float* fc_w = (const float*)d_in[1];
    const float* fc_b = (const float*)d_in[2];
    float* out = (float*)d_out;
    __hip_bfloat16* x = (__hip_bfloat16*)d_ws;                          // 4 MB
    unsigned short* fcswz = (unsigned short*)((char*)d_ws + (4 << 20)); // 32 KB

    hist_kernel<<<2048 + 8, 256, 0, stream>>>(frames, fc_w, x, fcswz);
    simfc_kernel<<<256, 512, 0, stream>>>((const unsigned short*)x, fcswz, fc_b, out);
}

// Round 9
// 43.803 us; speedup vs baseline: 1.4183x; 1.4183x over previous
//
#include <hip/hip_runtime.h>
#include <hip/hip_bf16.h>

#define NUM_BINS 512
#define T_LEN 256
#define B_LEN 16
#define WIN 101
#define HALF 50
#define NOUT 128

typedef __attribute__((ext_vector_type(8))) short short8;
typedef __attribute__((ext_vector_type(4))) float f32x4;

__device__ __forceinline__ unsigned short f2bf(float f) {
    unsigned u = __float_as_uint(f);
    u += 0x7fff + ((u >> 16) & 1);   // round-to-nearest-even
    return (unsigned short)(u >> 16);
}

// ---------------- Kernel 1: one wave = one frame (zero cross-wave coupling) --
// 4096 single-wave blocks (16/CU): each wave streams its 48 KB frame
// (16 iters x 3 dwordx4, 3 KB/wave/iter contiguous), scatters into a
// wave-private parity-split LDS histogram (idx = bin*2 + lane&1: even lanes
// hit even banks, odd lanes odd banks), then shfl_xor-butterfly reduces the
// sum of squares and writes one coalesced 1 KB bf16 row. No block barrier
// ever gates the VMEM stream; 16 independent wave-pipelines per CU overlap
// load bursts with atomic bursts. + 32 tail blocks: fc_w -> bf16 MFMA
// B-fragment layout [og][ks][kg][l15][e], zero-padded to K=128.
__global__ __launch_bounds__(64) void hist_kernel(const int* __restrict__ frames,
                                                  const float* __restrict__ fc_w,
                                                  __hip_bfloat16* __restrict__ xout,
                                                  unsigned short* __restrict__ fcswz) {
    const int bid = blockIdx.x;
    const int lane = threadIdx.x;   // 0..63

    if (bid >= 4096) {
        const int base = (bid - 4096) * 512 + lane * 8;
        const int l15 = (base >> 3) & 15;
        const int kg = (base >> 7) & 3;
        const int ks = (base >> 9) & 3;
        const int og = base >> 11;
        const int o = og * 16 + l15;
        short8 v;
        #pragma unroll
        for (int e = 0; e < 8; ++e) {
            const int w = ks * 32 + kg * 8 + e;
            v[e] = (short)((w < WIN) ? f2bf(fc_w[o * WIN + w]) : (unsigned short)0);
        }
        *(short8*)(fcswz + base) = v;
        return;
    }

    __shared__ int hist[2 * NUM_BINS];   // parity-interleaved: bin*2 + (lane&1)

    {
        const int4 z = {0, 0, 0, 0};
        #pragma unroll
        for (int i = 0; i < 4; ++i)
            *(int4*)(&hist[i * 256 + lane * 4]) = z;
    }
    __syncthreads();   // single-wave: cheap; orders zeroing vs atomics

    const int par = lane & 1;
    const int4* f4 = (const int4*)(frames + (size_t)bid * 12288);
    #pragma unroll 4
    for (int i = 0; i < 16; ++i) {
        const int q = (i * 64 + lane) * 3;   // pixel quad: 48 contiguous bytes
        int4 a = f4[q + 0];
        int4 b = f4[q + 1];
        int4 c = f4[q + 2];
        atomicAdd(&hist[(((a.x >> 5) << 7) | ((a.y >> 5) << 4) | ((a.z >> 5) << 1)) | par], 1);
        atomicAdd(&hist[(((a.w >> 5) << 7) | ((b.x >> 5) << 4) | ((b.y >> 5) << 1)) | par], 1);
        atomicAdd(&hist[(((b.z >> 5) << 7) | ((b.w >> 5) << 4) | ((c.x >> 5) << 1)) | par], 1);
        atomicAdd(&hist[(((c.y >> 5) << 7) | ((c.z >> 5) << 4) | ((c.w >> 5) << 1)) | par], 1);
    }
    __syncthreads();   // drain this wave's atomics before readback

    // lane owns bins [lane*8, lane*8+8) = hist indices [lane*16, lane*16+16)
    int h[8];
    {
        const int4* hp = (const int4*)(&hist[lane * 16]);
        int4 a = hp[0], b = hp[1], c = hp[2], d = hp[3];
        h[0] = a.x + a.y; h[1] = a.z + a.w;
        h[2] = b.x + b.y; h[3] = b.z + b.w;
        h[4] = c.x + c.y; h[5] = c.z + c.w;
        h[6] = d.x + d.y; h[7] = d.z + d.w;
    }
    float ss = 0.0f;
    #pragma unroll
    for (int j = 0; j < 8; ++j) ss += (float)h[j] * (float)h[j];
    #pragma unroll
    for (int off = 1; off < 64; off <<= 1) ss += __shfl_xor(ss, off, 64);
    const float inv = 1.0f / sqrtf(ss);

    short8 v;
    #pragma unroll
    for (int j = 0; j < 8; ++j) v[j] = (short)f2bf((float)h[j] * inv);
    *(short8*)((unsigned short*)xout + (size_t)bid * NUM_BINS + lane * 8) = v;
}

// ---------------- Kernel 2: MFMA banded sim + window extract + MFMA FC -------
// grid = 256 blocks (XCD = b%8 keeps per-XCD x slice L2-hot), 512 threads.
// Phase 1: wave j computes s-tile j of the 16x128 sim band (16 MFMAs, K=512).
// Phase 2: diagonal extract win[i][w] = sim[i][i+w] -> bf16, zero-pad w>=101.
// Phase 3: wave j computes 16 FC outputs via pre-swizzled bf16 fc_w (4 MFMAs).
__global__ __launch_bounds__(512) void simfc_kernel(const unsigned short* __restrict__ x,
                                                    const unsigned short* __restrict__ fcswz,
                                                    const float* __restrict__ fc_b,
                                                    float* __restrict__ out) {
    __shared__ float sim_lds[16 * 132];
    __shared__ unsigned short win_lds[16 * 136];

    const int bid = blockIdx.x;
    const int b = bid & 15;
    const int tt = bid >> 4;
    const int t0 = tt * 16;
    const int tid = threadIdx.x;
    const int lane = tid & 63;
    const int wave = tid >> 6;   // 0..7
    const int l15 = lane & 15;
    const int kg = lane >> 4;    // k-chunk 0..3

    const unsigned short* xb = x + (size_t)b * T_LEN * NUM_BINS;

    // ---- Phase 1: s-tile `wave`: cols s = t0-50+16*wave .. +15
    {
        f32x4 acc = {0.f, 0.f, 0.f, 0.f};
        const short8 zero8 = {0, 0, 0, 0, 0, 0, 0, 0};
        const int rowA = t0 + l15;
        const int rb = t0 - HALF + 16 * wave + l15;
        const bool vv = (rb >= 0) && (rb < T_LEN);
        const int rc = min(max(rb, 0), T_LEN - 1);
        const unsigned short* pa = xb + (size_t)rowA * NUM_BINS + kg * 8;
        const unsigned short* ps = xb + (size_t)rc * NUM_BINS + kg * 8;
        #pragma unroll
        for (int ks = 0; ks < 16; ++ks) {
            short8 a  = *(const short8*)(pa + ks * 32);
            short8 bb = *(const short8*)(ps + ks * 32);
            bb = vv ? bb : zero8;
            acc = __builtin_amdgcn_mfma_f32_16x16x32_bf16(a, bb, acc, 0, 0, 0);
        }
        #pragma unroll
        for (int r = 0; r < 4; ++r)
            sim_lds[(kg * 4 + r) * 132 + wave * 16 + l15] = acc[r];
    }
    __syncthreads();

    // ---- Phase 2: windowed[i][w] = sim[i][i+w], bf16, zero-pad w>=101.
    if (tid < 256) {
        const int i = tid >> 4;
        const int w8 = (tid & 15) * 8;
        short8 v;
        #pragma unroll
        for (int e = 0; e < 8; ++e) {
            const int w = w8 + e;
            const float fv = (w < WIN) ? sim_lds[i * 132 + i + w] : 0.0f;
            v[e] = (short)f2bf(fv);
        }
        *(short8*)(&win_lds[i * 136 + w8]) = v;
    }
    __syncthreads();

    // ---- Phase 3: wave owns outputs o = wave*16 + l15, K=128 MFMA.
    {
        f32x4 o0 = {0.f, 0.f, 0.f, 0.f};
        const int o = wave * 16 + l15;
        #pragma unroll
        for (int ks = 0; ks < 4; ++ks) {
            short8 a = *(const short8*)(&win_lds[l15 * 136 + ks * 32 + kg * 8]);
            short8 b0 = *(const short8*)(fcswz + ((((wave * 4 + ks) * 4 + kg) * 16 + l15) * 8));
            o0 = __builtin_amdgcn_mfma_f32_16x16x32_bf16(a, b0, o0, 0, 0, 0);
        }
        const float bias = fc_b[o];
        float* ob = out + ((size_t)b * T_LEN + t0) * NOUT;
        #pragma unroll
        for (int r = 0; r < 4; ++r)
            ob[(kg * 4 + r) * NOUT + o] = fmaxf(o0[r] + bias, 0.0f);
    }
}

extern "C" void kernel_launch(void* const* d_in, const int* in_sizes, int n_in,
                              void* d_out, int out_size, void* d_ws, size_t ws_size,
                              hipStream_t stream) {
    const int* frames = (const int*)d_in[0];
    const float* fc_w = (const float*)d_in[1];
    const float* fc_b = (const float*)d_in[2];
    float* out = (float*)d_out;
    __hip_bfloat16* x = (__hip_bfloat16*)d_ws;                          // 4 MB
    unsigned short* fcswz = (unsigned short*)((char*)d_ws + (4 << 20)); // 32 KB

    hist_kernel<<<4096 + 32, 64, 0, stream>>>(frames, fc_w, x, fcswz);
    simfc_kernel<<<256, 512, 0, stream>>>((const unsigned short*)x, fcswz, fc_b, out);
}